// Round 6
// baseline (3008.554 us; speedup 1.0000x reference)
//
#include <hip/hip_runtime.h>
#include <math.h>

#define T 32000
#define B 8
#define RES 32
#define SKIPC 32
#define NDIL 10
#define NLAYERS 20

typedef __attribute__((ext_vector_type(2))) float float2v;

// ---------------- fast transcendentals (v_exp_f32 / v_rcp_f32) ----------------
__device__ __forceinline__ float fast_rcp(float x) { return __builtin_amdgcn_rcpf(x); }
__device__ __forceinline__ float fast_exp2(float x) { return __builtin_amdgcn_exp2f(x); }
__device__ __forceinline__ float fast_sigmoid(float x) {
    return fast_rcp(1.f + fast_exp2(-1.4426950408889634f * x));
}
__device__ __forceinline__ float fast_tanh(float x) {
    return 1.f - 2.f * fast_rcp(1.f + fast_exp2(2.8853900817779268f * x));
}

// ---------------- weight repack for half-split res_layer ----------------
// res_w1: [10][64][32][3] -> w1p: [10][2][32][3][2][16]
//   (l, o, c, k) -> (l, h=(o%32)/16, c, k, p=o/32, j=o%16)
// res_w2: [10][64][32]    -> w2p: [10][2][32][2][16]
__global__ void repack_weights(const float* __restrict__ w1,
                               const float* __restrict__ w2,
                               float* __restrict__ w1p,
                               float* __restrict__ w2p) {
    int idx = blockIdx.x * blockDim.x + threadIdx.x;
    if (idx < NDIL * 64 * 32 * 3) {
        int i = idx;
        int k = i % 3; i /= 3;
        int c = i % 32; i /= 32;
        int o = i % 64; i /= 64;
        int l = i;
        int p = o / 32, rem = o % 32, h = rem / 16, j = rem % 16;
        w1p[(((((l * 2 + h) * 32 + c) * 3 + k) * 2 + p) * 16) + j] = w1[idx];
    }
    if (idx < NDIL * 64 * 32) {
        int i = idx;
        int c = i % 32; i /= 32;
        int o = i % 64; i /= 64;
        int l = i;
        int p = o / 32, rem = o % 32, h = rem / 16, j = rem % 16;
        w2p[((((l * 2 + h) * 32 + c) * 2 + p) * 16) + j] = w2[idx];
    }
}

// ---------------- conv1: [B,1,T] -> [B,32,T], k=3 causal ----------------
__global__ void conv1_kernel(const float* __restrict__ x,
                             const float* __restrict__ w,   // [32][1][3]
                             float* __restrict__ h) {
    int t = blockIdx.x * blockDim.x + threadIdx.x;
    int b = blockIdx.y;
    if (t >= T) return;
    const float* xb = x + (size_t)b * T;
    float x2 = xb[t];
    float x1 = (t >= 1) ? xb[t - 1] : 0.f;
    float x0 = (t >= 2) ? xb[t - 2] : 0.f;
#pragma unroll
    for (int o = 0; o < RES; o++) {
        float v = w[o * 3 + 0] * x0 + w[o * 3 + 1] * x1 + w[o * 3 + 2] * x2;
        h[((size_t)(b * RES + o)) * T + t] = v;
    }
}

// ---------------- residual layer, half-split (R4 structure) ---------------
// Block = 256 threads = 128 t-positions x 2 halves (half wave-uniform).
// R6: plain affine loops with #pragma unroll 4 (compiler schedules the
// pipeline — R5's manual rotation doubled VALU count and regressed),
// float2 accumulators/weights to target v_pk_fma_f32 dual-issue.
template <bool FIRST>
__global__ __launch_bounds__(256) void res_layer(
        const float* __restrict__ h_in, float* __restrict__ h_out,
        float* __restrict__ skip,
        const float* __restrict__ w1p,   // [2][32][3][2][16] this layer
        const float* __restrict__ w2p,   // [2][32][2][16] this layer
        int d) {
    __shared__ float g_lds[32][128];

    int tid = threadIdx.x;
    int t_idx = tid & 127;
    int half = __builtin_amdgcn_readfirstlane(tid >> 7);  // wave-uniform -> SGPR
    int t = blockIdx.x * 128 + t_idx;
    int b = blockIdx.y;

    const float* hb  = h_in + (size_t)b * RES * T;
    const float* w1h = w1p + half * (32 * 3 * 2 * 16);
    const float* w2h = w2p + half * (32 * 2 * 16);

    // clamped tap indices (safe addresses; value zeroed by select)
    int t1 = t - d;     bool v1 = t1 >= 0; int t1c = v1 ? t1 : 0;
    int t0 = t - 2 * d; bool v0 = t0 >= 0; int t0c = v0 ? t0 : 0;

    // acc as float2 pairs: acc0[j] covers output channels 2j,2j+1 (p=0 path)
    float2v acc0[8], acc1[8];
#pragma unroll
    for (int j = 0; j < 8; j++) { acc0[j] = (float2v)(0.f); acc1[j] = (float2v)(0.f); }

#pragma unroll 4
    for (int c = 0; c < RES; c++) {
        const float* hc = hb + (size_t)c * T;
        float x2 = hc[t];
        float x1 = v1 ? hc[t1c] : 0.f;
        float x0 = v0 ? hc[t0c] : 0.f;
        float2v xx2 = {x2, x2}, xx1 = {x1, x1}, xx0 = {x0, x0};
        // float2 view of [k][p][16]: p0k0=[0..8) p1k0=[8..16) p0k1=[16..24)
        // p1k1=[24..32) p0k2=[32..40) p1k2=[40..48)
        const float2v* wc = (const float2v*)(w1h + c * 96);
#pragma unroll
        for (int j = 0; j < 8; j++) {
            acc0[j] += wc[j] * xx0 + wc[16 + j] * xx1 + wc[32 + j] * xx2;
            acc1[j] += wc[8 + j] * xx0 + wc[24 + j] * xx1 + wc[40 + j] * xx2;
        }
    }

    // gate (local: this thread owns both members of each (o, o+32) pair)
#pragma unroll
    for (int j = 0; j < 16; j++) {
        float a0 = acc0[j >> 1][j & 1];
        float a1 = acc1[j >> 1][j & 1];
        float g = fast_tanh(a0) * fast_sigmoid(a1);
        g_lds[16 * half + j][t_idx] = g;
    }
    __syncthreads();

    int ob = 16 * half;

    // prefetch skip RMW values; latency hidden under the 1x1 loop
    float skv[16];
    if (!FIRST) {
#pragma unroll
        for (int j = 0; j < 16; j++)
            skv[j] = skip[((size_t)(b * SKIPC + ob + j)) * T + t];
    }

    // 1x1: this half produces h_out channels [16h,16h+16) and skip same range
    float2v zr[8], zs[8];
#pragma unroll
    for (int j = 0; j < 8; j++) { zr[j] = (float2v)(0.f); zs[j] = (float2v)(0.f); }
#pragma unroll 4
    for (int c = 0; c < RES; c++) {
        float gc = g_lds[c][t_idx];
        float2v gg = {gc, gc};
        const float2v* vc = (const float2v*)(w2h + c * 32);  // p0=[0..8) p1=[8..16)
#pragma unroll
        for (int j = 0; j < 8; j++) {
            zr[j] += vc[j] * gg;
            zs[j] += vc[8 + j] * gg;
        }
    }

    // skip writes first (skv already resident)
#pragma unroll
    for (int j = 0; j < 16; j++) {
        size_t off = ((size_t)(b * SKIPC + ob + j)) * T + t;
        float zsv = zs[j >> 1][j & 1];
        if (FIRST) skip[off] = zsv;
        else       skip[off] = skv[j] + zsv;
    }
    // h_out: batch the h_in loads, then add+store
    float hv[16];
#pragma unroll
    for (int j = 0; j < 16; j++)
        hv[j] = h_in[((size_t)(b * RES + ob + j)) * T + t];
#pragma unroll
    for (int j = 0; j < 16; j++) {
        size_t off = ((size_t)(b * RES + ob + j)) * T + t;
        h_out[off] = hv[j] + zr[j >> 1][j & 1];
    }
}

// ---------------- post2: tanh(skip) -> conv 32->16 k3 -> tanh ----------------
__global__ void post2_kernel(const float* __restrict__ skip,
                             const float* __restrict__ w,    // [16][32][3]
                             float* __restrict__ out16) {
    int t = blockIdx.x * blockDim.x + threadIdx.x;
    int b = blockIdx.y;
    float acc[16];
#pragma unroll
    for (int o = 0; o < 16; o++) acc[o] = 0.f;
    for (int c = 0; c < 32; c++) {
        const float* sc = skip + ((size_t)(b * 32 + c)) * T;
        float v2 = fast_tanh(sc[t]);
        float v1 = (t >= 1) ? fast_tanh(sc[t - 1]) : 0.f;
        float v0 = (t >= 2) ? fast_tanh(sc[t - 2]) : 0.f;
#pragma unroll
        for (int o = 0; o < 16; o++) {
            const float* wo = w + (o * 32 + c) * 3;
            acc[o] += wo[0] * v0 + wo[1] * v1 + wo[2] * v2;
        }
    }
#pragma unroll
    for (int o = 0; o < 16; o++)
        out16[((size_t)(b * 16 + o)) * T + t] = fast_tanh(acc[o]);
}

// ---------------- post3: conv 16->8 k3 -> tanh ----------------
__global__ void post3_kernel(const float* __restrict__ in16,
                             const float* __restrict__ w,    // [8][16][3]
                             float* __restrict__ out8) {
    int t = blockIdx.x * blockDim.x + threadIdx.x;
    int b = blockIdx.y;
    float acc[8];
#pragma unroll
    for (int o = 0; o < 8; o++) acc[o] = 0.f;
    for (int c = 0; c < 16; c++) {
        const float* sc = in16 + ((size_t)(b * 16 + c)) * T;
        float v2 = sc[t];
        float v1 = (t >= 1) ? sc[t - 1] : 0.f;
        float v0 = (t >= 2) ? sc[t - 2] : 0.f;
#pragma unroll
        for (int o = 0; o < 8; o++) {
            const float* wo = w + (o * 16 + c) * 3;
            acc[o] += wo[0] * v0 + wo[1] * v1 + wo[2] * v2;
        }
    }
#pragma unroll
    for (int o = 0; o < 8; o++)
        out8[((size_t)(b * 8 + o)) * T + t] = fast_tanh(acc[o]);
}

// ---------------- post4: conv 8->1 k3 -> tanh ----------------
__global__ void post4_kernel(const float* __restrict__ in8,
                             const float* __restrict__ w,    // [1][8][3]
                             float* __restrict__ out1) {
    int t = blockIdx.x * blockDim.x + threadIdx.x;
    int b = blockIdx.y;
    float acc = 0.f;
#pragma unroll
    for (int c = 0; c < 8; c++) {
        const float* sc = in8 + ((size_t)(b * 8 + c)) * T;
        float v2 = sc[t];
        float v1 = (t >= 1) ? sc[t - 1] : 0.f;
        float v0 = (t >= 2) ? sc[t - 2] : 0.f;
        const float* wo = w + c * 3;
        acc += wo[0] * v0 + wo[1] * v1 + wo[2] * v2;
    }
    out1[(size_t)b * T + t] = fast_tanh(acc);
}

// ---------------- vnn head: lin(k=16) + quadratic Volterra ----------------
__global__ void vnn_kernel(const float* __restrict__ in1,   // [B][T]
                           const float* __restrict__ w1,    // [1][1][16]
                           const float* __restrict__ w2,    // [6][1][16]
                           float* __restrict__ out) {       // [B][T]
    int t = blockIdx.x * blockDim.x + threadIdx.x;
    int b = blockIdx.y;
    const float* xb = in1 + (size_t)b * T;
    float tap[16];
#pragma unroll
    for (int k = 0; k < 16; k++) {
        int ti = t - 15 + k;
        tap[k] = (ti >= 0) ? xb[ti] : 0.f;
    }
    float lin = 0.f;
#pragma unroll
    for (int k = 0; k < 16; k++) lin += w1[k] * tap[k];
    float s[6];
#pragma unroll
    for (int q = 0; q < 6; q++) {
        float a = 0.f;
#pragma unroll
        for (int k = 0; k < 16; k++) a += w2[q * 16 + k] * tap[k];
        s[q] = a;
    }
    float quad = s[0] * s[3] + s[1] * s[4] + s[2] * s[5];
    out[(size_t)b * T + t] = lin + quad;
}

extern "C" void kernel_launch(void* const* d_in, const int* in_sizes, int n_in,
                              void* d_out, int out_size, void* d_ws, size_t ws_size,
                              hipStream_t stream) {
    const float* x       = (const float*)d_in[0];
    const float* conv1_w = (const float*)d_in[1];
    const float* res_w1  = (const float*)d_in[2];
    const float* res_w2  = (const float*)d_in[3];
    const float* post2_w = (const float*)d_in[4];
    const float* post3_w = (const float*)d_in[5];
    const float* post4_w = (const float*)d_in[6];
    const float* vnn1_w  = (const float*)d_in[7];
    const float* vnn2_w  = (const float*)d_in[8];
    float* out = (float*)d_out;

    // workspace layout (bytes)
    char* ws = (char*)d_ws;
    const size_t SZ_H    = (size_t)B * RES * T * 4;     // 32.768 MB
    const size_t SZ_O16  = (size_t)B * 16 * T * 4;
    const size_t SZ_O8   = (size_t)B * 8 * T * 4;
    const size_t SZ_O1   = (size_t)B * 1 * T * 4;
    float* hA    = (float*)(ws);
    float* hB    = (float*)(ws + SZ_H);
    float* skip  = (float*)(ws + 2 * SZ_H);
    float* out16 = (float*)(ws + 3 * SZ_H);
    float* out8  = (float*)(ws + 3 * SZ_H + SZ_O16);
    float* out1  = (float*)(ws + 3 * SZ_H + SZ_O16 + SZ_O8);
    float* w1p   = (float*)(ws + 3 * SZ_H + SZ_O16 + SZ_O8 + SZ_O1);
    float* w2p   = (float*)(ws + 3 * SZ_H + SZ_O16 + SZ_O8 + SZ_O1
                               + (size_t)NDIL * 64 * 32 * 3 * 4);

    dim3 blk(256);
    dim3 grd(T / 256, B);     // pre/post kernels: 125 x 8
    dim3 grdR(T / 128, B);    // res layers: 250 x 8 (2000 blocks)

    repack_weights<<<dim3((NDIL * 64 * 32 * 3 + 255) / 256), blk, 0, stream>>>(
        res_w1, res_w2, w1p, w2p);

    conv1_kernel<<<grd, blk, 0, stream>>>(x, conv1_w, hA);

    const float* cur = hA;
    float* nxt = hB;
    for (int l = 0; l < NLAYERS; l++) {
        int i = l % NDIL;
        int d = 1 << i;
        const float* w1l = w1p + (size_t)i * 2 * 32 * 3 * 2 * 16;
        const float* w2l = w2p + (size_t)i * 2 * 32 * 2 * 16;
        if (l == 0)
            res_layer<true><<<grdR, blk, 0, stream>>>(cur, nxt, skip, w1l, w2l, d);
        else
            res_layer<false><<<grdR, blk, 0, stream>>>(cur, nxt, skip, w1l, w2l, d);
        const float* tmp = nxt;
        nxt = (float*)cur;
        cur = tmp;
    }

    post2_kernel<<<grd, blk, 0, stream>>>(skip, post2_w, out16);
    post3_kernel<<<grd, blk, 0, stream>>>(out16, post3_w, out8);
    post4_kernel<<<grd, blk, 0, stream>>>(out8, post4_w, out1);
    vnn_kernel<<<grd, blk, 0, stream>>>(out1, vnn1_w, vnn2_w, out);
}

// Round 7
// 928.641 us; speedup vs baseline: 3.2397x; 3.2397x over previous
//
#include <hip/hip_runtime.h>
#include <math.h>

#define T 32000
#define B 8
#define RES 32
#define SKIPC 32
#define NDIL 10
#define NLAYERS 20

typedef __attribute__((ext_vector_type(8))) _Float16 half8;
typedef __attribute__((ext_vector_type(4))) _Float16 half4;
typedef __attribute__((ext_vector_type(4))) float float4v;

// ---------------- fast transcendentals ----------------
__device__ __forceinline__ float fast_rcp(float x) { return __builtin_amdgcn_rcpf(x); }
__device__ __forceinline__ float fast_exp2(float x) { return __builtin_amdgcn_exp2f(x); }
__device__ __forceinline__ float fast_sigmoid(float x) {
    return fast_rcp(1.f + fast_exp2(-1.4426950408889634f * x));
}
__device__ __forceinline__ float fast_tanh(float x) {
    return 1.f - 2.f * fast_rcp(1.f + fast_exp2(2.8853900817779268f * x));
}

// ---------------- weight repack to fp16 ----------------
// res_w1: [10][64][32][3] -> w1f: [10][3][64][32] fp16  (tap-major, c contig)
// res_w2: [10][64][32]    -> w2f: [10][64][32] fp16     (same order)
__global__ void repack_weights_f16(const float* __restrict__ w1,
                                   const float* __restrict__ w2,
                                   _Float16* __restrict__ w1f,
                                   _Float16* __restrict__ w2f) {
    int idx = blockIdx.x * blockDim.x + threadIdx.x;
    if (idx < NDIL * 3 * 64 * 32) {
        int i = idx;
        int c = i % 32; i /= 32;
        int o = i % 64; i /= 64;
        int kt = i % 3; i /= 3;
        int l = i;
        w1f[idx] = (_Float16)w1[((l * 64 + o) * 32 + c) * 3 + kt];
    }
    if (idx < NDIL * 64 * 32) {
        w2f[idx] = (_Float16)w2[idx];
    }
}

// ---------------- conv1: [B,1,T] -> [B,32,T], k=3 causal ----------------
__global__ void conv1_kernel(const float* __restrict__ x,
                             const float* __restrict__ w,   // [32][1][3]
                             float* __restrict__ h) {
    int t = blockIdx.x * blockDim.x + threadIdx.x;
    int b = blockIdx.y;
    if (t >= T) return;
    const float* xb = x + (size_t)b * T;
    float x2 = xb[t];
    float x1 = (t >= 1) ? xb[t - 1] : 0.f;
    float x0 = (t >= 2) ? xb[t - 2] : 0.f;
#pragma unroll
    for (int o = 0; o < RES; o++) {
        float v = w[o * 3 + 0] * x0 + w[o * 3 + 1] * x1 + w[o * 3 + 2] * x2;
        h[((size_t)(b * RES + o)) * T + t] = v;
    }
}

// ---------------- residual layer via f16 MFMA ----------------
// Block = 256 threads = 4 waves; t-tile of 128 positions (t0 = bx*128).
// GEMM1: Y[64 o][128 n] = sum_kt W1[kt][64x32] * X[kt][32 c][128 n]
//   X staged in LDS as [n][c] fp16 (B-frag reads contiguous-k, m97 pattern).
// gate: lane-local pairing of M-tiles (0,2),(1,3); G -> LDS [n][c] fp16.
// GEMM2: Z[64][128] = W2[64x32] * G. Epilogue: h_out = h_in + Z[:32] (fp32),
// skip += Z[32:] (fp32 RMW). h/skip stay fp32 in HBM; fp16 only at MFMA edge.
template <bool FIRST>
__global__ __launch_bounds__(256) void res_layer_mfma(
        const float* __restrict__ h_in, float* __restrict__ h_out,
        float* __restrict__ skip,
        const _Float16* __restrict__ w1l,   // [3][64][32] this layer
        const _Float16* __restrict__ w2l,   // [64][32] this layer
        int d) {
    __shared__ _Float16 Xs[3][128][40];   // [tap][n][c], row 80B (16B aligned)
    __shared__ _Float16 Gs[128][40];

    const int tid = threadIdx.x;
    const int t0 = blockIdx.x * 128;
    const int b = blockIdx.y;
    const float* hb = h_in + (size_t)b * RES * T;

    // ---- stage X taps: thread (n = tid&127, cg = tid>>7) loads 16 channels ----
    {
        const int n = tid & 127;
        const int cg = tid >> 7;        // 0 or 1
        const int c0 = cg * 16;
        const int t = t0 + n;
        if (t0 >= 2 * d) {              // interior block: no bounds checks
#pragma unroll
            for (int kt = 0; kt < 3; kt++) {
                const int ts = t - (2 - kt) * d;
                const float* hp = hb + ts;
                half8 p0, p1;
#pragma unroll
                for (int i = 0; i < 8; i++) {
                    p0[i] = (_Float16)hp[(size_t)(c0 + i) * T];
                    p1[i] = (_Float16)hp[(size_t)(c0 + 8 + i) * T];
                }
                *(half8*)&Xs[kt][n][c0] = p0;
                *(half8*)&Xs[kt][n][c0 + 8] = p1;
            }
        } else {
#pragma unroll
            for (int kt = 0; kt < 3; kt++) {
                const int ts = t - (2 - kt) * d;
                const bool ok = ts >= 0;
                const float* hp = hb + (ok ? ts : 0);
                half8 p0, p1;
#pragma unroll
                for (int i = 0; i < 8; i++) {
                    float a = ok ? hp[(size_t)(c0 + i) * T] : 0.f;
                    float bb = ok ? hp[(size_t)(c0 + 8 + i) * T] : 0.f;
                    p0[i] = (_Float16)a;
                    p1[i] = (_Float16)bb;
                }
                *(half8*)&Xs[kt][n][c0] = p0;
                *(half8*)&Xs[kt][n][c0 + 8] = p1;
            }
        }
    }
    __syncthreads();

    const int lane = tid & 63;
    const int wv = tid >> 6;        // wave id 0..3
    const int n0 = wv * 32;         // wave's n base (covers n0..n0+31)
    const int lcol = lane & 15;
    const int q = lane >> 4;        // quad 0..3

    // ---- GEMM1: conv ----
    float4v acc[4][2];
#pragma unroll
    for (int mt = 0; mt < 4; mt++)
#pragma unroll
        for (int nt = 0; nt < 2; nt++) acc[mt][nt] = (float4v)(0.f);

    half8 bf[2][3];
#pragma unroll
    for (int nt = 0; nt < 2; nt++)
#pragma unroll
        for (int kt = 0; kt < 3; kt++)
            bf[nt][kt] = *(const half8*)&Xs[kt][n0 + nt * 16 + lcol][q * 8];

#pragma unroll
    for (int mt = 0; mt < 4; mt++) {
#pragma unroll
        for (int kt = 0; kt < 3; kt++) {
            half8 af = *(const half8*)(w1l + ((size_t)(kt * 64 + mt * 16 + lcol) * 32 + q * 8));
#pragma unroll
            for (int nt = 0; nt < 2; nt++)
                acc[mt][nt] = __builtin_amdgcn_mfma_f32_16x16x32_f16(
                    af, bf[nt][kt], acc[mt][nt], 0, 0, 0);
        }
    }

    // ---- gate: channel o (tiles 0,1) pairs with o+32 (tiles 2,3), same lane/reg ----
#pragma unroll
    for (int pp = 0; pp < 2; pp++) {
#pragma unroll
        for (int nt = 0; nt < 2; nt++) {
            half4 gh;
#pragma unroll
            for (int r = 0; r < 4; r++) {
                float a0 = acc[pp][nt][r];
                float a1 = acc[pp + 2][nt][r];
                gh[r] = (_Float16)(fast_tanh(a0) * fast_sigmoid(a1));
            }
            // c = pp*16 + q*4 + r ; n = n0 + nt*16 + lcol
            *(half4*)&Gs[n0 + nt * 16 + lcol][pp * 16 + q * 4] = gh;
        }
    }
    __syncthreads();

    // ---- skip prefetch (latency hides under GEMM2) ----
    const int tcol = t0 + n0;   // wave's t base
    float skv[16];
    if (!FIRST) {
#pragma unroll
        for (int mt = 0; mt < 2; mt++)
#pragma unroll
            for (int nt = 0; nt < 2; nt++)
#pragma unroll
                for (int r = 0; r < 4; r++) {
                    int o = mt * 16 + q * 4 + r;
                    int t = tcol + nt * 16 + lcol;
                    skv[(mt * 2 + nt) * 4 + r] =
                        skip[((size_t)(b * SKIPC + o)) * T + t];
                }
    }

    // ---- GEMM2: 1x1 ----
    float4v zacc[4][2];
#pragma unroll
    for (int mt = 0; mt < 4; mt++)
#pragma unroll
        for (int nt = 0; nt < 2; nt++) zacc[mt][nt] = (float4v)(0.f);

    half8 gb[2];
#pragma unroll
    for (int nt = 0; nt < 2; nt++)
        gb[nt] = *(const half8*)&Gs[n0 + nt * 16 + lcol][q * 8];

#pragma unroll
    for (int mt = 0; mt < 4; mt++) {
        half8 af = *(const half8*)(w2l + ((size_t)(mt * 16 + lcol) * 32 + q * 8));
#pragma unroll
        for (int nt = 0; nt < 2; nt++)
            zacc[mt][nt] = __builtin_amdgcn_mfma_f32_16x16x32_f16(
                af, gb[nt], zacc[mt][nt], 0, 0, 0);
    }

    // ---- epilogue ----
    // h_out channels: tiles 0,1 -> o = mt*16 + q*4 + r
    float hv[16];
#pragma unroll
    for (int mt = 0; mt < 2; mt++)
#pragma unroll
        for (int nt = 0; nt < 2; nt++)
#pragma unroll
            for (int r = 0; r < 4; r++) {
                int o = mt * 16 + q * 4 + r;
                int t = tcol + nt * 16 + lcol;
                hv[(mt * 2 + nt) * 4 + r] = h_in[((size_t)(b * RES + o)) * T + t];
            }
#pragma unroll
    for (int mt = 0; mt < 2; mt++)
#pragma unroll
        for (int nt = 0; nt < 2; nt++)
#pragma unroll
            for (int r = 0; r < 4; r++) {
                int o = mt * 16 + q * 4 + r;
                int t = tcol + nt * 16 + lcol;
                h_out[((size_t)(b * RES + o)) * T + t] =
                    hv[(mt * 2 + nt) * 4 + r] + zacc[mt][nt][r];
            }
    // skip channels: tiles 2,3 -> o = (mt-2)*16 + q*4 + r
#pragma unroll
    for (int mt = 0; mt < 2; mt++)
#pragma unroll
        for (int nt = 0; nt < 2; nt++)
#pragma unroll
            for (int r = 0; r < 4; r++) {
                int o = mt * 16 + q * 4 + r;
                int t = tcol + nt * 16 + lcol;
                size_t off = ((size_t)(b * SKIPC + o)) * T + t;
                float z = zacc[mt + 2][nt][r];
                if (FIRST) skip[off] = z;
                else       skip[off] = skv[(mt * 2 + nt) * 4 + r] + z;
            }
}

// ---------------- post2: tanh(skip) -> conv 32->16 k3 -> tanh ----------------
__global__ void post2_kernel(const float* __restrict__ skip,
                             const float* __restrict__ w,    // [16][32][3]
                             float* __restrict__ out16) {
    int t = blockIdx.x * blockDim.x + threadIdx.x;
    int b = blockIdx.y;
    float acc[16];
#pragma unroll
    for (int o = 0; o < 16; o++) acc[o] = 0.f;
    for (int c = 0; c < 32; c++) {
        const float* sc = skip + ((size_t)(b * 32 + c)) * T;
        float v2 = fast_tanh(sc[t]);
        float v1 = (t >= 1) ? fast_tanh(sc[t - 1]) : 0.f;
        float v0 = (t >= 2) ? fast_tanh(sc[t - 2]) : 0.f;
#pragma unroll
        for (int o = 0; o < 16; o++) {
            const float* wo = w + (o * 32 + c) * 3;
            acc[o] += wo[0] * v0 + wo[1] * v1 + wo[2] * v2;
        }
    }
#pragma unroll
    for (int o = 0; o < 16; o++)
        out16[((size_t)(b * 16 + o)) * T + t] = fast_tanh(acc[o]);
}

// ---------------- post3: conv 16->8 k3 -> tanh ----------------
__global__ void post3_kernel(const float* __restrict__ in16,
                             const float* __restrict__ w,    // [8][16][3]
                             float* __restrict__ out8) {
    int t = blockIdx.x * blockDim.x + threadIdx.x;
    int b = blockIdx.y;
    float acc[8];
#pragma unroll
    for (int o = 0; o < 8; o++) acc[o] = 0.f;
    for (int c = 0; c < 16; c++) {
        const float* sc = in16 + ((size_t)(b * 16 + c)) * T;
        float v2 = sc[t];
        float v1 = (t >= 1) ? sc[t - 1] : 0.f;
        float v0 = (t >= 2) ? sc[t - 2] : 0.f;
#pragma unroll
        for (int o = 0; o < 8; o++) {
            const float* wo = w + (o * 16 + c) * 3;
            acc[o] += wo[0] * v0 + wo[1] * v1 + wo[2] * v2;
        }
    }
#pragma unroll
    for (int o = 0; o < 8; o++)
        out8[((size_t)(b * 8 + o)) * T + t] = fast_tanh(acc[o]);
}

// ---------------- post4: conv 8->1 k3 -> tanh ----------------
__global__ void post4_kernel(const float* __restrict__ in8,
                             const float* __restrict__ w,    // [1][8][3]
                             float* __restrict__ out1) {
    int t = blockIdx.x * blockDim.x + threadIdx.x;
    int b = blockIdx.y;
    float acc = 0.f;
#pragma unroll
    for (int c = 0; c < 8; c++) {
        const float* sc = in8 + ((size_t)(b * 8 + c)) * T;
        float v2 = sc[t];
        float v1 = (t >= 1) ? sc[t - 1] : 0.f;
        float v0 = (t >= 2) ? sc[t - 2] : 0.f;
        const float* wo = w + c * 3;
        acc += wo[0] * v0 + wo[1] * v1 + wo[2] * v2;
    }
    out1[(size_t)b * T + t] = fast_tanh(acc);
}

// ---------------- vnn head: lin(k=16) + quadratic Volterra ----------------
__global__ void vnn_kernel(const float* __restrict__ in1,   // [B][T]
                           const float* __restrict__ w1,    // [1][1][16]
                           const float* __restrict__ w2,    // [6][1][16]
                           float* __restrict__ out) {       // [B][T]
    int t = blockIdx.x * blockDim.x + threadIdx.x;
    int b = blockIdx.y;
    const float* xb = in1 + (size_t)b * T;
    float tap[16];
#pragma unroll
    for (int k = 0; k < 16; k++) {
        int ti = t - 15 + k;
        tap[k] = (ti >= 0) ? xb[ti] : 0.f;
    }
    float lin = 0.f;
#pragma unroll
    for (int k = 0; k < 16; k++) lin += w1[k] * tap[k];
    float s[6];
#pragma unroll
    for (int q = 0; q < 6; q++) {
        float a = 0.f;
#pragma unroll
        for (int k = 0; k < 16; k++) a += w2[q * 16 + k] * tap[k];
        s[q] = a;
    }
    float quad = s[0] * s[3] + s[1] * s[4] + s[2] * s[5];
    out[(size_t)b * T + t] = lin + quad;
}

extern "C" void kernel_launch(void* const* d_in, const int* in_sizes, int n_in,
                              void* d_out, int out_size, void* d_ws, size_t ws_size,
                              hipStream_t stream) {
    const float* x       = (const float*)d_in[0];
    const float* conv1_w = (const float*)d_in[1];
    const float* res_w1  = (const float*)d_in[2];
    const float* res_w2  = (const float*)d_in[3];
    const float* post2_w = (const float*)d_in[4];
    const float* post3_w = (const float*)d_in[5];
    const float* post4_w = (const float*)d_in[6];
    const float* vnn1_w  = (const float*)d_in[7];
    const float* vnn2_w  = (const float*)d_in[8];
    float* out = (float*)d_out;

    // workspace layout (bytes)
    char* ws = (char*)d_ws;
    const size_t SZ_H    = (size_t)B * RES * T * 4;     // 32.768 MB
    const size_t SZ_O16  = (size_t)B * 16 * T * 4;
    const size_t SZ_O8   = (size_t)B * 8 * T * 4;
    const size_t SZ_O1   = (size_t)B * 1 * T * 4;
    float*     hA    = (float*)(ws);
    float*     hB    = (float*)(ws + SZ_H);
    float*     skip  = (float*)(ws + 2 * SZ_H);
    float*     out16 = (float*)(ws + 3 * SZ_H);
    float*     out8  = (float*)(ws + 3 * SZ_H + SZ_O16);
    float*     out1  = (float*)(ws + 3 * SZ_H + SZ_O16 + SZ_O8);
    _Float16*  w1f   = (_Float16*)(ws + 3 * SZ_H + SZ_O16 + SZ_O8 + SZ_O1);
    _Float16*  w2f   = (_Float16*)(ws + 3 * SZ_H + SZ_O16 + SZ_O8 + SZ_O1
                                      + (size_t)NDIL * 3 * 64 * 32 * 2);

    dim3 blk(256);
    dim3 grd(T / 256, B);     // pre/post kernels: 125 x 8
    dim3 grdR(T / 128, B);    // res layers: 250 x 8 (2000 blocks)

    repack_weights_f16<<<dim3((NDIL * 3 * 64 * 32 + 255) / 256), blk, 0, stream>>>(
        res_w1, res_w2, w1f, w2f);

    conv1_kernel<<<grd, blk, 0, stream>>>(x, conv1_w, hA);

    const float* cur = hA;
    float* nxt = hB;
    for (int l = 0; l < NLAYERS; l++) {
        int i = l % NDIL;
        int d = 1 << i;
        const _Float16* w1l = w1f + (size_t)i * 3 * 64 * 32;
        const _Float16* w2l = w2f + (size_t)i * 64 * 32;
        if (l == 0)
            res_layer_mfma<true><<<grdR, blk, 0, stream>>>(cur, nxt, skip, w1l, w2l, d);
        else
            res_layer_mfma<false><<<grdR, blk, 0, stream>>>(cur, nxt, skip, w1l, w2l, d);
        const float* tmp = nxt;
        nxt = (float*)cur;
        cur = tmp;
    }

    post2_kernel<<<grd, blk, 0, stream>>>(skip, post2_w, out16);
    post3_kernel<<<grd, blk, 0, stream>>>(out16, post3_w, out8);
    post4_kernel<<<grd, blk, 0, stream>>>(out8, post4_w, out1);
    vnn_kernel<<<grd, blk, 0, stream>>>(out1, vnn1_w, vnn2_w, out);
}